// Round 1
// baseline (225.639 us; speedup 1.0000x reference)
//
#include <hip/hip_runtime.h>
#include <stdint.h>

#define T_DIM 256
#define K_DIM 3072
#define N_DIM 3072
#define R_DIM 32
#define KG    48      // K / GROUP
#define NCHUNK 49     // 48 weight chunks + 1 lora/pad chunk
#define BN    64

typedef __bf16 bf16x8 __attribute__((ext_vector_type(8)));
typedef float  f32x4  __attribute__((ext_vector_type(4)));

// round-to-nearest-even fp32 -> bf16 (raw ushort)
__device__ __forceinline__ unsigned short f2bf(float f) {
    unsigned u = __builtin_bit_cast(unsigned, f);
    unsigned rounding = 0x7FFFu + ((u >> 16) & 1u);
    return (unsigned short)((u + rounding) >> 16);
}

// ---------------- K0: W_tail [N][64] bf16 = [lora_up | zeros] ----------------
__global__ void build_wtail(const float* __restrict__ lora_up,
                            unsigned short* __restrict__ Wt) {
    int idx = blockIdx.x * 256 + threadIdx.x;   // over N*64
    int n = idx >> 6, j = idx & 63;
    float v = (j < R_DIM) ? lora_up[n * R_DIM + j] : 0.f;
    Wt[idx] = f2bf(v);
}

// ---------------- K1: per-token quant + lora_mid -> A'' [49][256][64] bf16 ---
__global__ __launch_bounds__(256) void quant_lora(
        const float* __restrict__ x, const float* __restrict__ lora_down,
        unsigned short* __restrict__ Ap) {
    __shared__ float xs[K_DIM];
    int t = blockIdx.x;
    const float4* xr = (const float4*)(x + (size_t)t * K_DIM);
    float4* xs4 = (float4*)xs;
    for (int i = threadIdx.x; i < K_DIM / 4; i += 256) xs4[i] = xr[i];
    __syncthreads();
    int wave = threadIdx.x >> 6, lane = threadIdx.x & 63;
    // fake-quant per group; chunk-major write: A''[g][t][lane]
    for (int g = wave; g < KG; g += 4) {
        float v = xs[g * 64 + lane];
        float a = fabsf(v);
        #pragma unroll
        for (int off = 32; off; off >>= 1) a = fmaxf(a, __shfl_xor(a, off));
        float scale = fmaxf(a / 7.0f, 1e-8f);
        float q = rintf(v / scale);
        q = fminf(fmaxf(q, -8.f), 7.f);
        Ap[(g * T_DIM + t) * 64 + lane] = f2bf(q * scale);
    }
    // lora_mid[t][r] = sum_k x[t][k] * lora_down[r][k]; wave w does r=w*8..w*8+7
    for (int rr = 0; rr < 8; ++rr) {
        int r = wave * 8 + rr;
        const float* ld = lora_down + (size_t)r * K_DIM;
        float s = 0.f;
        for (int k = lane; k < K_DIM; k += 64) s += xs[k] * ld[k];
        #pragma unroll
        for (int off = 32; off; off >>= 1) s += __shfl_xor(s, off);
        if (lane == 0) Ap[(48 * T_DIM + t) * 64 + r] = f2bf(s);
    }
    if (threadIdx.x < 32) Ap[(48 * T_DIM + t) * 64 + 32 + threadIdx.x] = 0;
}

// ---------------- K2: split-K GEMM, dequant-on-the-fly, bf16 MFMA ------------
// grid (48 n-tiles, 4 k-splits), 256 threads. M-tile = 256 (all tokens).
__global__ __launch_bounds__(256) void gemm_main(
        const unsigned short* __restrict__ Ap,   // [49][256][64] bf16
        const int*            __restrict__ qweight, // [N][K] codes 0..15
        const float*          __restrict__ wscales, // [N][48]
        const unsigned short* __restrict__ Wt,      // [N][64] bf16
        const float*          __restrict__ bias,    // [N]
        float*                __restrict__ out) {   // [T][N] fp32
    __shared__ short As[T_DIM * 64];  // 32 KB
    __shared__ short Bs[BN * 64];     //  8 KB
    int nblk  = blockIdx.x;           // 0..47
    int split = blockIdx.y;           // 0..3
    int c0 = split * 12;
    int c1 = (split == 3) ? NCHUNK : c0 + 12;
    int tid = threadIdx.x;
    int lane = tid & 63, wv = tid >> 6;
    int mrow = lane & 15, quad = lane >> 4;
    int n_row = tid >> 2, seg = tid & 3;
    const int nbase = nblk * BN;

    f32x4 acc[4][4];
    f32x4 zero = {0.f, 0.f, 0.f, 0.f};
    #pragma unroll
    for (int i = 0; i < 4; ++i)
        #pragma unroll
        for (int j = 0; j < 4; ++j) acc[i][j] = zero;

    for (int kt = c0; kt < c1; ++kt) {
        __syncthreads();
        // stage A: thread stages row `tid` of the chunk (128 B, coalesced)
        {
            const uint4* gA = (const uint4*)(Ap + (size_t)kt * (T_DIM * 64)) + tid * 8;
            uint4* sA = ((uint4*)As) + tid * 8;
            #pragma unroll
            for (int i = 0; i < 8; ++i) sA[i] = gA[i];
        }
        // stage B: 4 threads per weight row; dequant int4 codes -> bf16
        if (kt < 48) {
            const int* gq = qweight + (size_t)(nbase + n_row) * K_DIM + kt * 64 + seg * 16;
            float wsv = wscales[(nbase + n_row) * KG + kt];
            int4 c[4];
            #pragma unroll
            for (int i = 0; i < 4; ++i) c[i] = ((const int4*)gq)[i];
            const int* ci = (const int*)c;
            alignas(16) unsigned short wb[16];
            #pragma unroll
            for (int j = 0; j < 16; ++j) wb[j] = f2bf((float)(ci[j] - 8) * wsv);
            uint4* sB = (uint4*)&Bs[n_row * 64 + seg * 16];
            sB[0] = ((const uint4*)wb)[0];
            sB[1] = ((const uint4*)wb)[1];
        } else {
            const uint4* gw = (const uint4*)(Wt + (size_t)(nbase + n_row) * 64) + seg * 2;
            uint4* sB = (uint4*)&Bs[n_row * 64 + seg * 16];
            sB[0] = gw[0];
            sB[1] = gw[1];
        }
        __syncthreads();
        // compute: wave wv covers rows [wv*64, wv*64+64)
        #pragma unroll
        for (int ks = 0; ks < 64; ks += 32) {
            bf16x8 a[4], b[4];
            #pragma unroll
            for (int mt = 0; mt < 4; ++mt)
                a[mt] = *(const bf16x8*)&As[(wv * 64 + mt * 16 + mrow) * 64 + ks + quad * 8];
            #pragma unroll
            for (int nt = 0; nt < 4; ++nt)
                b[nt] = *(const bf16x8*)&Bs[(nt * 16 + mrow) * 64 + ks + quad * 8];
            #pragma unroll
            for (int mt = 0; mt < 4; ++mt)
                #pragma unroll
                for (int nt = 0; nt < 4; ++nt)
                    acc[mt][nt] = __builtin_amdgcn_mfma_f32_16x16x32_bf16(
                        a[mt], b[nt], acc[mt][nt], 0, 0, 0);
        }
    }
    // epilogue: atomic partial reduction; bias added exactly once (split 3)
    #pragma unroll
    for (int nt = 0; nt < 4; ++nt) {
        int n = nbase + nt * 16 + mrow;             // C col = lane & 15
        float bv = (split == 3) ? bias[n] : 0.f;
        #pragma unroll
        for (int mt = 0; mt < 4; ++mt) {
            int row0 = wv * 64 + mt * 16 + quad * 4; // C row = quad*4 + reg
            #pragma unroll
            for (int r = 0; r < 4; ++r)
                atomicAdd(&out[(size_t)(row0 + r) * N_DIM + n], acc[mt][nt][r] + bv);
        }
    }
}

extern "C" void kernel_launch(void* const* d_in, const int* in_sizes, int n_in,
                              void* d_out, int out_size, void* d_ws, size_t ws_size,
                              hipStream_t stream) {
    const float* x         = (const float*)d_in[0];
    const int*   qweight   = (const int*)d_in[1];
    const float* wscales   = (const float*)d_in[2];
    const float* lora_down = (const float*)d_in[3];
    const float* lora_up   = (const float*)d_in[4];
    const float* bias      = (const float*)d_in[5];
    float* out = (float*)d_out;

    unsigned short* Ap = (unsigned short*)d_ws;                       // 49*256*64*2 B
    unsigned short* Wt = (unsigned short*)((char*)d_ws + (size_t)NCHUNK * T_DIM * 64 * 2);

    hipMemsetAsync(d_out, 0, (size_t)T_DIM * N_DIM * sizeof(float), stream);
    build_wtail<<<(N_DIM * 64) / 256, 256, 0, stream>>>(lora_up, Wt);
    quant_lora<<<T_DIM, 256, 0, stream>>>(x, lora_down, Ap);
    gemm_main<<<dim3(48, 4), 256, 0, stream>>>(Ap, qweight, wscales, Wt, bias, out);
}

// Round 2
// 143.285 us; speedup vs baseline: 1.5748x; 1.5748x over previous
//
#include <hip/hip_runtime.h>
#include <stdint.h>

#define T_DIM 256
#define K_DIM 3072
#define N_DIM 3072
#define R_DIM 32
#define KG    48      // K / GROUP
#define NCHUNK 49     // 48 weight chunks + 1 lora/pad chunk
#define BN    64
#define NSPLIT 8      // gemm k-splits

typedef __bf16 bf16x8 __attribute__((ext_vector_type(8)));
typedef float  f32x4  __attribute__((ext_vector_type(4)));
typedef unsigned short u16x8 __attribute__((ext_vector_type(8)));

// round-to-nearest-even fp32 -> bf16 (raw ushort)
__device__ __forceinline__ unsigned short f2bf(float f) {
    unsigned u = __builtin_bit_cast(unsigned, f);
    unsigned rounding = 0x7FFFu + ((u >> 16) & 1u);
    return (unsigned short)((u + rounding) >> 16);
}

__device__ __forceinline__ bf16x8 cvt8(const float* p) {
    float4 lo = ((const float4*)p)[0], hi = ((const float4*)p)[1];
    u16x8 u;
    u[0] = f2bf(lo.x); u[1] = f2bf(lo.y); u[2] = f2bf(lo.z); u[3] = f2bf(lo.w);
    u[4] = f2bf(hi.x); u[5] = f2bf(hi.y); u[6] = f2bf(hi.z); u[7] = f2bf(hi.w);
    return __builtin_bit_cast(bf16x8, u);
}

// ---------------- K0: W_tail [N][64] bf16 = [lora_up | zeros] ----------------
__global__ void build_wtail(const float* __restrict__ lora_up,
                            unsigned short* __restrict__ Wt) {
    int idx = blockIdx.x * 256 + threadIdx.x;   // over N*64
    int n = idx >> 6, j = idx & 63;
    float v = (j < R_DIM) ? lora_up[n * R_DIM + j] : 0.f;
    Wt[idx] = f2bf(v);
}

// ---------------- K1: per-(token,group) fake-quant, wave per group -----------
__global__ __launch_bounds__(256) void quant_act(
        const float* __restrict__ x, unsigned short* __restrict__ Ap) {
    int widx = blockIdx.x * 4 + (threadIdx.x >> 6);   // 0 .. T*KG-1
    int lane = threadIdx.x & 63;
    int t = widx / KG, g = widx % KG;
    float v = x[(size_t)t * K_DIM + g * 64 + lane];
    float a = fabsf(v);
    #pragma unroll
    for (int off = 32; off; off >>= 1) a = fmaxf(a, __shfl_xor(a, off));
    float scale = fmaxf(a / 7.0f, 1e-8f);
    float q = rintf(v / scale);
    q = fminf(fmaxf(q, -8.f), 7.f);
    Ap[((size_t)g * T_DIM + t) * 64 + lane] = f2bf(q * scale);
}

// ---------------- K2: lora_mid = x @ lora_down^T via MFMA, split-K ----------
// grid 16 blocks; block b covers k in [b*192, b*192+192). atomicAdd into Lm.
__global__ __launch_bounds__(256) void lora_mid(
        const float* __restrict__ x, const float* __restrict__ lora_down,
        float* __restrict__ Lm) {                     // [T][R] fp32, pre-zeroed
    int kb = blockIdx.x;
    int lane = threadIdx.x & 63, wv = threadIdx.x >> 6;
    int mrow = lane & 15, quad = lane >> 4;
    f32x4 acc[4][2];
    f32x4 zero = {0.f, 0.f, 0.f, 0.f};
    #pragma unroll
    for (int i = 0; i < 4; ++i) { acc[i][0] = zero; acc[i][1] = zero; }
    #pragma unroll
    for (int ki = 0; ki < 6; ++ki) {
        int k0 = kb * 192 + ki * 32 + quad * 8;
        bf16x8 a[4], b[2];
        #pragma unroll
        for (int mt = 0; mt < 4; ++mt)
            a[mt] = cvt8(x + (size_t)(wv * 64 + mt * 16 + mrow) * K_DIM + k0);
        #pragma unroll
        for (int nt = 0; nt < 2; ++nt)
            b[nt] = cvt8(lora_down + (size_t)(nt * 16 + mrow) * K_DIM + k0);
        #pragma unroll
        for (int mt = 0; mt < 4; ++mt)
            #pragma unroll
            for (int nt = 0; nt < 2; ++nt)
                acc[mt][nt] = __builtin_amdgcn_mfma_f32_16x16x32_bf16(
                    a[mt], b[nt], acc[mt][nt], 0, 0, 0);
    }
    #pragma unroll
    for (int mt = 0; mt < 4; ++mt)
        #pragma unroll
        for (int nt = 0; nt < 2; ++nt)
            #pragma unroll
            for (int r = 0; r < 4; ++r)
                atomicAdd(&Lm[(size_t)(wv * 64 + mt * 16 + quad * 4 + r) * R_DIM
                              + nt * 16 + mrow], acc[mt][nt][r]);
}

// ---------------- K3: pack Lm -> Ap chunk 48 (bf16, zero-padded) ------------
__global__ void pack_lora(const float* __restrict__ Lm,
                          unsigned short* __restrict__ Ap) {
    int idx = blockIdx.x * 256 + threadIdx.x;   // over T*64
    int t = idx >> 6, j = idx & 63;
    float v = (j < R_DIM) ? Lm[t * R_DIM + j] : 0.f;
    Ap[((size_t)48 * T_DIM + t) * 64 + j] = f2bf(v);
}

// ---------------- K4: split-K GEMM, dequant-on-the-fly, bf16 MFMA ------------
// grid (48 n-tiles, NSPLIT k-splits), 256 threads. M-tile = 256 (all tokens).
__global__ __launch_bounds__(256) void gemm_main(
        const unsigned short* __restrict__ Ap,      // [49][256][64] bf16
        const int*            __restrict__ qweight, // [N][K] codes 0..15
        const float*          __restrict__ wscales, // [N][48]
        const unsigned short* __restrict__ Wt,      // [N][64] bf16
        const float*          __restrict__ bias,    // [N]
        float*                __restrict__ out) {   // [T][N] fp32
    __shared__ short As[T_DIM * 64];  // 32 KB
    __shared__ short Bs[BN * 64];     //  8 KB
    int nblk  = blockIdx.x;           // 0..47
    int split = blockIdx.y;           // 0..NSPLIT-1
    int c0 = split * 6;
    int c1 = (split == NSPLIT - 1) ? NCHUNK : c0 + 6;
    int tid = threadIdx.x;
    int lane = tid & 63, wv = tid >> 6;
    int mrow = lane & 15, quad = lane >> 4;
    int n_row = tid >> 2, seg = tid & 3;
    const int nbase = nblk * BN;

    f32x4 acc[4][4];
    f32x4 zero = {0.f, 0.f, 0.f, 0.f};
    #pragma unroll
    for (int i = 0; i < 4; ++i)
        #pragma unroll
        for (int j = 0; j < 4; ++j) acc[i][j] = zero;

    for (int kt = c0; kt < c1; ++kt) {
        __syncthreads();
        // stage A: thread stages row `tid` of the chunk (128 B, coalesced)
        {
            const uint4* gA = (const uint4*)(Ap + (size_t)kt * (T_DIM * 64)) + tid * 8;
            uint4* sA = ((uint4*)As) + tid * 8;
            #pragma unroll
            for (int i = 0; i < 8; ++i) sA[i] = gA[i];
        }
        // stage B: 4 threads per weight row; dequant int4 codes -> bf16
        if (kt < 48) {
            const int* gq = qweight + (size_t)(nbase + n_row) * K_DIM + kt * 64 + seg * 16;
            float wsv = wscales[(nbase + n_row) * KG + kt];
            int4 c[4];
            #pragma unroll
            for (int i = 0; i < 4; ++i) c[i] = ((const int4*)gq)[i];
            const int* ci = (const int*)c;
            alignas(16) unsigned short wb[16];
            #pragma unroll
            for (int j = 0; j < 16; ++j) wb[j] = f2bf((float)(ci[j] - 8) * wsv);
            uint4* sB = (uint4*)&Bs[n_row * 64 + seg * 16];
            sB[0] = ((const uint4*)wb)[0];
            sB[1] = ((const uint4*)wb)[1];
        } else {
            const uint4* gw = (const uint4*)(Wt + (size_t)(nbase + n_row) * 64) + seg * 2;
            uint4* sB = (uint4*)&Bs[n_row * 64 + seg * 16];
            sB[0] = gw[0];
            sB[1] = gw[1];
        }
        __syncthreads();
        // compute: wave wv covers rows [wv*64, wv*64+64)
        #pragma unroll
        for (int ks = 0; ks < 64; ks += 32) {
            bf16x8 a[4], b[4];
            #pragma unroll
            for (int mt = 0; mt < 4; ++mt)
                a[mt] = *(const bf16x8*)&As[(wv * 64 + mt * 16 + mrow) * 64 + ks + quad * 8];
            #pragma unroll
            for (int nt = 0; nt < 4; ++nt)
                b[nt] = *(const bf16x8*)&Bs[(nt * 16 + mrow) * 64 + ks + quad * 8];
            #pragma unroll
            for (int mt = 0; mt < 4; ++mt)
                #pragma unroll
                for (int nt = 0; nt < 4; ++nt)
                    acc[mt][nt] = __builtin_amdgcn_mfma_f32_16x16x32_bf16(
                        a[mt], b[nt], acc[mt][nt], 0, 0, 0);
        }
    }
    // epilogue: atomic partial reduction; bias added exactly once (last split)
    #pragma unroll
    for (int nt = 0; nt < 4; ++nt) {
        int n = nbase + nt * 16 + mrow;             // C col = lane & 15
        float bv = (split == NSPLIT - 1) ? bias[n] : 0.f;
        #pragma unroll
        for (int mt = 0; mt < 4; ++mt) {
            int row0 = wv * 64 + mt * 16 + quad * 4; // C row = quad*4 + reg
            #pragma unroll
            for (int r = 0; r < 4; ++r)
                atomicAdd(&out[(size_t)(row0 + r) * N_DIM + n], acc[mt][nt][r] + bv);
        }
    }
}

extern "C" void kernel_launch(void* const* d_in, const int* in_sizes, int n_in,
                              void* d_out, int out_size, void* d_ws, size_t ws_size,
                              hipStream_t stream) {
    const float* x         = (const float*)d_in[0];
    const int*   qweight   = (const int*)d_in[1];
    const float* wscales   = (const float*)d_in[2];
    const float* lora_down = (const float*)d_in[3];
    const float* lora_up   = (const float*)d_in[4];
    const float* bias      = (const float*)d_in[5];
    float* out = (float*)d_out;

    char* wsp = (char*)d_ws;
    unsigned short* Ap = (unsigned short*)wsp;                 // 49*256*64*2 B
    wsp += (size_t)NCHUNK * T_DIM * 64 * 2;
    unsigned short* Wt = (unsigned short*)wsp;                 // 3072*64*2 B
    wsp += (size_t)N_DIM * 64 * 2;
    float* Lm = (float*)wsp;                                   // 256*32*4 B

    hipMemsetAsync(d_out, 0, (size_t)T_DIM * N_DIM * sizeof(float), stream);
    hipMemsetAsync(Lm, 0, (size_t)T_DIM * R_DIM * sizeof(float), stream);
    build_wtail<<<(N_DIM * 64) / 256, 256, 0, stream>>>(lora_up, Wt);
    quant_act<<<(T_DIM * KG) / 4, 256, 0, stream>>>(x, Ap);
    lora_mid<<<16, 256, 0, stream>>>(x, lora_down, Lm);
    pack_lora<<<(T_DIM * 64) / 256, 256, 0, stream>>>(Lm, Ap);
    gemm_main<<<dim3(48, NSPLIT), 256, 0, stream>>>(Ap, qweight, wscales, Wt, bias, out);
}

// Round 3
// 140.641 us; speedup vs baseline: 1.6044x; 1.0188x over previous
//
#include <hip/hip_runtime.h>
#include <stdint.h>

#define T_DIM 256
#define K_DIM 3072
#define N_DIM 3072
#define R_DIM 32
#define KG    48      // K / GROUP
#define NCHUNK 49     // 48 weight chunks + 1 lora/pad chunk
#define NSPLIT 8      // gemm k-splits

typedef __bf16 bf16x8 __attribute__((ext_vector_type(8)));
typedef float  f32x4  __attribute__((ext_vector_type(4)));
typedef unsigned short u16x8 __attribute__((ext_vector_type(8)));

// round-to-nearest-even fp32 -> bf16 (raw ushort)
__device__ __forceinline__ unsigned short f2bf(float f) {
    unsigned u = __builtin_bit_cast(unsigned, f);
    unsigned rounding = 0x7FFFu + ((u >> 16) & 1u);
    return (unsigned short)((u + rounding) >> 16);
}

__device__ __forceinline__ bf16x8 cvt8(const float* p) {
    float4 lo = ((const float4*)p)[0], hi = ((const float4*)p)[1];
    u16x8 u;
    u[0] = f2bf(lo.x); u[1] = f2bf(lo.y); u[2] = f2bf(lo.z); u[3] = f2bf(lo.w);
    u[4] = f2bf(hi.x); u[5] = f2bf(hi.y); u[6] = f2bf(hi.z); u[7] = f2bf(hi.w);
    return __builtin_bit_cast(bf16x8, u);
}

// async global->LDS, 16 bytes per lane. LDS dest must be wave-uniform + lane*16.
__device__ __forceinline__ void glds16(const void* gptr, void* lptr) {
    __builtin_amdgcn_global_load_lds(
        (const __attribute__((address_space(1))) unsigned int*)gptr,
        (__attribute__((address_space(3))) unsigned int*)lptr,
        16, 0, 0);
}

// ---------------- K0: W_tail, unit-major: Wt[nblk][u(8)][nl(64)] 16B units ---
__global__ void build_wtail(const float* __restrict__ lora_up,
                            unsigned short* __restrict__ Wt) {
    int idx = blockIdx.x * 256 + threadIdx.x;   // over N*64
    int n = idx >> 6, j = idx & 63;
    int nblk = n >> 6, nl = n & 63;
    float v = (j < R_DIM) ? lora_up[n * R_DIM + j] : 0.f;
    Wt[(((size_t)nblk * 8 + (j >> 3)) * 64 + nl) * 8 + (j & 7)] = f2bf(v);
}

// ---------------- K1: fake-quant -> Ap unit-major [chunk][u(8)][t(256)] -----
__global__ __launch_bounds__(256) void quant_act(
        const float* __restrict__ x, unsigned short* __restrict__ Ap) {
    int widx = blockIdx.x * 4 + (threadIdx.x >> 6);   // 0 .. T*KG-1
    int lane = threadIdx.x & 63;
    int t = widx / KG, g = widx % KG;
    float v = x[(size_t)t * K_DIM + g * 64 + lane];
    float a = fabsf(v);
    #pragma unroll
    for (int off = 32; off; off >>= 1) a = fmaxf(a, __shfl_xor(a, off));
    float scale = fmaxf(a / 7.0f, 1e-8f);
    float q = rintf(v / scale);
    q = fminf(fmaxf(q, -8.f), 7.f);
    Ap[(((size_t)g * 8 + (lane >> 3)) * 256 + t) * 8 + (lane & 7)] = f2bf(q * scale);
}

// ---------------- K2: lora_mid, 96 blocks, one 32-wide k-step each ----------
__global__ __launch_bounds__(256) void lora_mid(
        const float* __restrict__ x, const float* __restrict__ lora_down,
        float* __restrict__ Lm) {                     // [T][R] fp32, pre-zeroed
    int lane = threadIdx.x & 63, wv = threadIdx.x >> 6;
    int mrow = lane & 15, quad = lane >> 4;
    int k0 = blockIdx.x * 32 + quad * 8;
    bf16x8 a[4], b[2];
    #pragma unroll
    for (int mt = 0; mt < 4; ++mt)
        a[mt] = cvt8(x + (size_t)(wv * 64 + mt * 16 + mrow) * K_DIM + k0);
    #pragma unroll
    for (int nt = 0; nt < 2; ++nt)
        b[nt] = cvt8(lora_down + (size_t)(nt * 16 + mrow) * K_DIM + k0);
    f32x4 acc[4][2];
    f32x4 zero = {0.f, 0.f, 0.f, 0.f};
    #pragma unroll
    for (int i = 0; i < 4; ++i) { acc[i][0] = zero; acc[i][1] = zero; }
    #pragma unroll
    for (int mt = 0; mt < 4; ++mt)
        #pragma unroll
        for (int nt = 0; nt < 2; ++nt)
            acc[mt][nt] = __builtin_amdgcn_mfma_f32_16x16x32_bf16(
                a[mt], b[nt], acc[mt][nt], 0, 0, 0);
    #pragma unroll
    for (int mt = 0; mt < 4; ++mt)
        #pragma unroll
        for (int nt = 0; nt < 2; ++nt)
            #pragma unroll
            for (int r = 0; r < 4; ++r)
                atomicAdd(&Lm[(size_t)(wv * 64 + mt * 16 + quad * 4 + r) * R_DIM
                              + nt * 16 + mrow], acc[mt][nt][r]);
}

// ---------------- K3: pack Lm -> Ap chunk 48 (bf16, zero-padded) ------------
__global__ void pack_lora(const float* __restrict__ Lm,
                          unsigned short* __restrict__ Ap) {
    int idx = blockIdx.x * 256 + threadIdx.x;   // over T*64
    int t = idx >> 6, j = idx & 63;
    float v = (j < R_DIM) ? Lm[t * R_DIM + j] : 0.f;
    Ap[((size_t)(384 + (j >> 3)) * 256 + t) * 8 + (j & 7)] = f2bf(v);
}

// ---------------- K4: pipelined split-K GEMM, glds A, reg-prefetch B --------
// grid (48 n-tiles, NSPLIT k-splits), 256 threads. M-tile = 256 (all tokens).
__global__ __launch_bounds__(256) void gemm_main(
        const uint4*          __restrict__ ApU,     // [49][8][256] 16B units
        const int*            __restrict__ qweight, // [N][K] codes 0..15
        const float*          __restrict__ wscales, // [N][48]
        const uint4*          __restrict__ WtU,     // [48][8][64] 16B units
        const float*          __restrict__ bias,    // [N]
        float*                __restrict__ out) {   // [T][N] fp32
    __shared__ uint4 AsU[2][2048];   // [u(8)][t(256)], double-buffered: 64 KB
    __shared__ uint4 BsU[2][512];    // [u(8)][n(64)],  double-buffered: 16 KB
    int nblk  = blockIdx.x;          // 0..47
    int split = blockIdx.y;          // 0..NSPLIT-1
    int c0 = split * 6;
    int c1 = (split == NSPLIT - 1) ? NCHUNK : c0 + 6;
    int tid = threadIdx.x;
    int lane = tid & 63, wv = tid >> 6;
    int mrow = lane & 15, quad = lane >> 4;
    int n_row = tid >> 2, seg = tid & 3;
    const int nbase = nblk * 64;
    const int* qrow = qweight + (size_t)(nbase + n_row) * K_DIM + seg * 16;
    const float* wsrow = wscales + (size_t)(nbase + n_row) * KG;

    f32x4 acc[4][4];
    f32x4 zero = {0.f, 0.f, 0.f, 0.f};
    #pragma unroll
    for (int i = 0; i < 4; ++i)
        #pragma unroll
        for (int j = 0; j < 4; ++j) acc[i][j] = zero;

    int4 bc[2][4];     // distance-2 qweight code prefetch
    float wsr[2];

    // prologue: A(c0) -> As[0] async; codes for c0 and c0+1 -> regs
    {
        const uint4* gA = ApU + (size_t)c0 * 2048;
        #pragma unroll
        for (int i = 0; i < 8; ++i)
            glds16(&gA[tid + i * 256], &AsU[0][tid + i * 256]);
        const int4* g0 = (const int4*)(qrow + c0 * 64);
        const int4* g1 = (const int4*)(qrow + (c0 + 1) * 64);
        #pragma unroll
        for (int i = 0; i < 4; ++i) { bc[0][i] = g0[i]; bc[1][i] = g1[i]; }
        wsr[0] = wsrow[c0];
        wsr[1] = wsrow[c0 + 1];
    }

    for (int kt = c0; kt < c1; ++kt) {
        int lc = kt - c0;
        int p = lc & 1;
        // dequant codes(kt) -> Bs[p]  (Bs[p] readers at kt-2 fenced by barrier kt-1)
        if (kt < 48) {
            float w = wsr[p];
            const int* ci = (const int*)bc[p];
            alignas(16) unsigned short wb[16];
            #pragma unroll
            for (int j = 0; j < 16; ++j) wb[j] = f2bf((float)(ci[j] - 8) * w);
            const uint4* w2 = (const uint4*)wb;
            BsU[p][(seg * 2 + 0) * 64 + n_row] = w2[0];
            BsU[p][(seg * 2 + 1) * 64 + n_row] = w2[1];
        }
        __syncthreads();   // drains glds A(kt) (+Wt glds), makes Bs[p] visible
        // post-barrier: issue prefetches that fly during MFMA(kt)
        if (kt + 2 < c1 && kt + 2 < 48) {     // codes, distance 2
            const int4* gq = (const int4*)(qrow + (kt + 2) * 64);
            #pragma unroll
            for (int i = 0; i < 4; ++i) bc[p][i] = gq[i];
            wsr[p] = wsrow[kt + 2];
        }
        if (kt + 1 < c1) {                    // A tile, distance 1 (async glds)
            const uint4* gA = ApU + (size_t)(kt + 1) * 2048;
            #pragma unroll
            for (int i = 0; i < 8; ++i)
                glds16(&gA[tid + i * 256], &AsU[p ^ 1][tid + i * 256]);
            if (kt + 1 == 48) {               // lora tail B via async glds
                #pragma unroll
                for (int j = 0; j < 2; ++j)
                    glds16(&WtU[(size_t)nblk * 512 + tid + j * 256],
                           &BsU[p ^ 1][tid + j * 256]);
            }
        }
        // MFMA over As[p], Bs[p]
        #pragma unroll
        for (int ks8 = 0; ks8 < 8; ks8 += 4) {
            bf16x8 a[4], b[4];
            #pragma unroll
            for (int mt = 0; mt < 4; ++mt)
                a[mt] = *(const bf16x8*)&AsU[p][(quad + ks8) * 256 + wv * 64 + mt * 16 + mrow];
            #pragma unroll
            for (int nt = 0; nt < 4; ++nt)
                b[nt] = *(const bf16x8*)&BsU[p][(quad + ks8) * 64 + nt * 16 + mrow];
            #pragma unroll
            for (int mt = 0; mt < 4; ++mt)
                #pragma unroll
                for (int nt = 0; nt < 4; ++nt)
                    acc[mt][nt] = __builtin_amdgcn_mfma_f32_16x16x32_bf16(
                        a[mt], b[nt], acc[mt][nt], 0, 0, 0);
        }
    }
    // epilogue: atomic partial reduction; bias added exactly once (last split)
    #pragma unroll
    for (int nt = 0; nt < 4; ++nt) {
        int n = nbase + nt * 16 + mrow;             // C col = lane & 15
        float bv = (split == NSPLIT - 1) ? bias[n] : 0.f;
        #pragma unroll
        for (int mt = 0; mt < 4; ++mt) {
            int row0 = wv * 64 + mt * 16 + quad * 4; // C row = quad*4 + reg
            #pragma unroll
            for (int r = 0; r < 4; ++r)
                atomicAdd(&out[(size_t)(row0 + r) * N_DIM + n], acc[mt][nt][r] + bv);
        }
    }
}

extern "C" void kernel_launch(void* const* d_in, const int* in_sizes, int n_in,
                              void* d_out, int out_size, void* d_ws, size_t ws_size,
                              hipStream_t stream) {
    const float* x         = (const float*)d_in[0];
    const int*   qweight   = (const int*)d_in[1];
    const float* wscales   = (const float*)d_in[2];
    const float* lora_down = (const float*)d_in[3];
    const float* lora_up   = (const float*)d_in[4];
    const float* bias      = (const float*)d_in[5];
    float* out = (float*)d_out;

    char* wsp = (char*)d_ws;
    unsigned short* Ap = (unsigned short*)wsp;                 // 49*2048*16 B
    wsp += (size_t)NCHUNK * 2048 * 16;
    unsigned short* Wt = (unsigned short*)wsp;                 // 48*512*16 B
    wsp += (size_t)48 * 512 * 16;
    float* Lm = (float*)wsp;                                   // 256*32*4 B

    hipMemsetAsync(d_out, 0, (size_t)T_DIM * N_DIM * sizeof(float), stream);
    hipMemsetAsync(Lm, 0, (size_t)T_DIM * R_DIM * sizeof(float), stream);
    build_wtail<<<(N_DIM * 64) / 256, 256, 0, stream>>>(lora_up, Wt);
    quant_act<<<(T_DIM * KG) / 4, 256, 0, stream>>>(x, Ap);
    lora_mid<<<K_DIM / 32, 256, 0, stream>>>(x, lora_down, Lm);
    pack_lora<<<(T_DIM * 64) / 256, 256, 0, stream>>>(Lm, Ap);
    gemm_main<<<dim3(48, NSPLIT), 256, 0, stream>>>(
        (const uint4*)Ap, qweight, wscales, (const uint4*)Wt, bias, out);
}

// Round 4
// 131.145 us; speedup vs baseline: 1.7205x; 1.0724x over previous
//
#include <hip/hip_runtime.h>
#include <stdint.h>

#define T_DIM 256
#define K_DIM 3072
#define N_DIM 3072
#define R_DIM 32
#define KG    48      // K / GROUP
#define NCHUNK 49     // 48 weight chunks + 1 lora/pad chunk
#define NSPLIT 4      // gemm k-splits (partial buffers, no atomics)

typedef __bf16 bf16x8 __attribute__((ext_vector_type(8)));
typedef float  f32x4  __attribute__((ext_vector_type(4)));
typedef unsigned short u16x8 __attribute__((ext_vector_type(8)));

// round-to-nearest-even fp32 -> bf16 (raw ushort)
__device__ __forceinline__ unsigned short f2bf(float f) {
    unsigned u = __builtin_bit_cast(unsigned, f);
    unsigned rounding = 0x7FFFu + ((u >> 16) & 1u);
    return (unsigned short)((u + rounding) >> 16);
}

__device__ __forceinline__ bf16x8 cvt8(const float* p) {
    float4 lo = ((const float4*)p)[0], hi = ((const float4*)p)[1];
    u16x8 u;
    u[0] = f2bf(lo.x); u[1] = f2bf(lo.y); u[2] = f2bf(lo.z); u[3] = f2bf(lo.w);
    u[4] = f2bf(hi.x); u[5] = f2bf(hi.y); u[6] = f2bf(hi.z); u[7] = f2bf(hi.w);
    return __builtin_bit_cast(bf16x8, u);
}

// async global->LDS, 16 bytes per lane. LDS dest must be wave-uniform + lane*16.
__device__ __forceinline__ void glds16(const void* gptr, void* lptr) {
    __builtin_amdgcn_global_load_lds(
        (const __attribute__((address_space(1))) unsigned int*)gptr,
        (__attribute__((address_space(3))) unsigned int*)lptr,
        16, 0, 0);
}

// ---------------- K-1: stream qweight once, pack to 4-bit nibbles -----------
// Barrier-free pure stream: this is the only kernel that touches the 37.7 MB.
__global__ __launch_bounds__(256) void pack_qw(
        const int* __restrict__ q, unsigned* __restrict__ Qp) {
    size_t i = (size_t)blockIdx.x * 256 + threadIdx.x;   // over N*K/8
    const int4* p = (const int4*)(q + i * 8);
    int4 a = p[0], b = p[1];
    unsigned w = (unsigned)(a.x & 15)        | ((unsigned)(a.y & 15) << 4)
               | ((unsigned)(a.z & 15) << 8) | ((unsigned)(a.w & 15) << 12)
               | ((unsigned)(b.x & 15) << 16)| ((unsigned)(b.y & 15) << 20)
               | ((unsigned)(b.z & 15) << 24)| ((unsigned)(b.w & 15) << 28);
    Qp[i] = w;
}

// ---------------- K0: W_tail, unit-major: Wt[nblk][u(8)][nl(64)] 16B units ---
__global__ void build_wtail(const float* __restrict__ lora_up,
                            unsigned short* __restrict__ Wt) {
    int idx = blockIdx.x * 256 + threadIdx.x;   // over N*64
    int n = idx >> 6, j = idx & 63;
    int nblk = n >> 6, nl = n & 63;
    float v = (j < R_DIM) ? lora_up[n * R_DIM + j] : 0.f;
    Wt[(((size_t)nblk * 8 + (j >> 3)) * 64 + nl) * 8 + (j & 7)] = f2bf(v);
}

// ---------------- K1: fake-quant -> Ap unit-major [chunk][u(8)][t(256)] -----
__global__ __launch_bounds__(256) void quant_act(
        const float* __restrict__ x, unsigned short* __restrict__ Ap) {
    int widx = blockIdx.x * 4 + (threadIdx.x >> 6);   // 0 .. T*KG-1
    int lane = threadIdx.x & 63;
    int t = widx / KG, g = widx % KG;
    float v = x[(size_t)t * K_DIM + g * 64 + lane];
    float a = fabsf(v);
    #pragma unroll
    for (int off = 32; off; off >>= 1) a = fmaxf(a, __shfl_xor(a, off));
    float scale = fmaxf(a / 7.0f, 1e-8f);
    float q = rintf(v / scale);
    q = fminf(fmaxf(q, -8.f), 7.f);
    Ap[(((size_t)g * 8 + (lane >> 3)) * 256 + t) * 8 + (lane & 7)] = f2bf(q * scale);
}

// ---------------- K2: lora_mid, 96 blocks, one 32-wide k-step each ----------
__global__ __launch_bounds__(256) void lora_mid(
        const float* __restrict__ x, const float* __restrict__ lora_down,
        float* __restrict__ Lm) {                     // [T][R] fp32, pre-zeroed
    int lane = threadIdx.x & 63, wv = threadIdx.x >> 6;
    int mrow = lane & 15, quad = lane >> 4;
    int k0 = blockIdx.x * 32 + quad * 8;
    bf16x8 a[4], b[2];
    #pragma unroll
    for (int mt = 0; mt < 4; ++mt)
        a[mt] = cvt8(x + (size_t)(wv * 64 + mt * 16 + mrow) * K_DIM + k0);
    #pragma unroll
    for (int nt = 0; nt < 2; ++nt)
        b[nt] = cvt8(lora_down + (size_t)(nt * 16 + mrow) * K_DIM + k0);
    f32x4 acc[4][2];
    f32x4 zero = {0.f, 0.f, 0.f, 0.f};
    #pragma unroll
    for (int i = 0; i < 4; ++i) { acc[i][0] = zero; acc[i][1] = zero; }
    #pragma unroll
    for (int mt = 0; mt < 4; ++mt)
        #pragma unroll
        for (int nt = 0; nt < 2; ++nt)
            acc[mt][nt] = __builtin_amdgcn_mfma_f32_16x16x32_bf16(
                a[mt], b[nt], acc[mt][nt], 0, 0, 0);
    #pragma unroll
    for (int mt = 0; mt < 4; ++mt)
        #pragma unroll
        for (int nt = 0; nt < 2; ++nt)
            #pragma unroll
            for (int r = 0; r < 4; ++r)
                atomicAdd(&Lm[(size_t)(wv * 64 + mt * 16 + quad * 4 + r) * R_DIM
                              + nt * 16 + mrow], acc[mt][nt][r]);
}

// ---------------- K3: pack Lm -> Ap chunk 48 (bf16, zero-padded) ------------
__global__ void pack_lora(const float* __restrict__ Lm,
                          unsigned short* __restrict__ Ap) {
    int idx = blockIdx.x * 256 + threadIdx.x;   // over T*64
    int t = idx >> 6, j = idx & 63;
    float v = (j < R_DIM) ? Lm[t * R_DIM + j] : 0.f;
    Ap[((size_t)(384 + (j >> 3)) * 256 + t) * 8 + (j & 7)] = f2bf(v);
}

// ---------------- K4: pipelined split-K GEMM, packed codes from cache -------
// grid (48 n-tiles, NSPLIT k-splits), 256 threads. M-tile = 256 (all tokens).
// Partials streamed to P[split] (no atomics).
__global__ __launch_bounds__(256) void gemm_main(
        const uint4*    __restrict__ ApU,     // [49][8][256] 16B units
        const unsigned* __restrict__ Qp,      // [N][K/8] packed nibbles
        const float*    __restrict__ wscales, // [N][48]
        const uint4*    __restrict__ WtU,     // [48][8][64] 16B units
        float*          __restrict__ P) {     // [NSPLIT][T][N] fp32 partials
    __shared__ uint4 AsU[2][2048];   // [u(8)][t(256)], double-buffered: 64 KB
    __shared__ uint4 BsU[2][512];    // [u(8)][n(64)],  double-buffered: 16 KB
    int nblk  = blockIdx.x;          // 0..47
    int split = blockIdx.y;          // 0..NSPLIT-1
    int c0 = split * 12;
    int c1 = (split == NSPLIT - 1) ? NCHUNK : c0 + 12;
    int tid = threadIdx.x;
    int lane = tid & 63, wv = tid >> 6;
    int mrow = lane & 15, quad = lane >> 4;
    int n_row = tid >> 2, seg = tid & 3;
    const int nbase = nblk * 64;
    // packed codes: 8 u32 per (row, chunk); seg covers 16 codes = 2 u32
    const unsigned* qprow = Qp + (size_t)(nbase + n_row) * (K_DIM / 8) + seg * 2;
    const float* wsrow = wscales + (size_t)(nbase + n_row) * KG;

    f32x4 acc[4][4];
    f32x4 zero = {0.f, 0.f, 0.f, 0.f};
    #pragma unroll
    for (int i = 0; i < 4; ++i)
        #pragma unroll
        for (int j = 0; j < 4; ++j) acc[i][j] = zero;

    uint2 ubc[2];      // distance-2 packed-code prefetch
    float wsr[2];

    // prologue
    {
        const uint4* gA = ApU + (size_t)c0 * 2048;
        #pragma unroll
        for (int i = 0; i < 8; ++i)
            glds16(&gA[tid + i * 256], &AsU[0][tid + i * 256]);
        ubc[0] = *(const uint2*)(qprow + c0 * 8);
        ubc[1] = *(const uint2*)(qprow + (c0 + 1) * 8);
        wsr[0] = wsrow[c0];
        wsr[1] = wsrow[c0 + 1];
    }

    for (int kt = c0; kt < c1; ++kt) {
        int lc = kt - c0;
        int p = lc & 1;
        // dequant packed codes(kt) -> Bs[p]
        if (kt < 48) {
            float w = wsr[p];
            unsigned u0 = ubc[p].x, u1 = ubc[p].y;
            alignas(16) unsigned short wb[16];
            #pragma unroll
            for (int j = 0; j < 8; ++j)
                wb[j] = f2bf((float)((int)((u0 >> (4 * j)) & 15u) - 8) * w);
            #pragma unroll
            for (int j = 0; j < 8; ++j)
                wb[8 + j] = f2bf((float)((int)((u1 >> (4 * j)) & 15u) - 8) * w);
            const uint4* w2 = (const uint4*)wb;
            BsU[p][(seg * 2 + 0) * 64 + n_row] = w2[0];
            BsU[p][(seg * 2 + 1) * 64 + n_row] = w2[1];
        }
        __syncthreads();   // drains glds A(kt) (+Wt glds), makes Bs[p] visible
        // post-barrier: prefetches that fly during MFMA(kt)
        if (kt + 2 < c1 && kt + 2 < 48) {     // packed codes, distance 2
            ubc[p] = *(const uint2*)(qprow + (kt + 2) * 8);
            wsr[p] = wsrow[kt + 2];
        }
        if (kt + 1 < c1) {                    // A tile, distance 1 (async glds)
            const uint4* gA = ApU + (size_t)(kt + 1) * 2048;
            #pragma unroll
            for (int i = 0; i < 8; ++i)
                glds16(&gA[tid + i * 256], &AsU[p ^ 1][tid + i * 256]);
            if (kt + 1 == 48) {               // lora tail B via async glds
                #pragma unroll
                for (int j = 0; j < 2; ++j)
                    glds16(&WtU[(size_t)nblk * 512 + tid + j * 256],
                           &BsU[p ^ 1][tid + j * 256]);
            }
        }
        // MFMA over As[p], Bs[p]
        #pragma unroll
        for (int ks8 = 0; ks8 < 8; ks8 += 4) {
            bf16x8 a[4], b[4];
            #pragma unroll
            for (int mt = 0; mt < 4; ++mt)
                a[mt] = *(const bf16x8*)&AsU[p][(quad + ks8) * 256 + wv * 64 + mt * 16 + mrow];
            #pragma unroll
            for (int nt = 0; nt < 4; ++nt)
                b[nt] = *(const bf16x8*)&BsU[p][(quad + ks8) * 64 + nt * 16 + mrow];
            #pragma unroll
            for (int mt = 0; mt < 4; ++mt)
                #pragma unroll
                for (int nt = 0; nt < 4; ++nt)
                    acc[mt][nt] = __builtin_amdgcn_mfma_f32_16x16x32_bf16(
                        a[mt], b[nt], acc[mt][nt], 0, 0, 0);
        }
    }
    // epilogue: streamed partial stores (no atomics, no contention)
    float* Pp = P + (size_t)split * (T_DIM * N_DIM);
    #pragma unroll
    for (int nt = 0; nt < 4; ++nt) {
        int n = nbase + nt * 16 + mrow;             // C col = lane & 15
        #pragma unroll
        for (int mt = 0; mt < 4; ++mt) {
            int row0 = wv * 64 + mt * 16 + quad * 4; // C row = quad*4 + reg
            #pragma unroll
            for (int r = 0; r < 4; ++r)
                Pp[(size_t)(row0 + r) * N_DIM + n] = acc[mt][nt][r];
        }
    }
}

// ---------------- K5: reduce partials + bias -> out -------------------------
__global__ __launch_bounds__(256) void reduce_out(
        const float4* __restrict__ P, const float* __restrict__ bias,
        float4* __restrict__ out) {
    int i = blockIdx.x * 256 + threadIdx.x;       // over T*N/4
    const int STRIDE = T_DIM * N_DIM / 4;
    float4 s0 = P[i], s1 = P[i + STRIDE], s2 = P[i + 2 * STRIDE], s3 = P[i + 3 * STRIDE];
    float4 bv = *(const float4*)&bias[(i * 4) % N_DIM];
    float4 o;
    o.x = s0.x + s1.x + s2.x + s3.x + bv.x;
    o.y = s0.y + s1.y + s2.y + s3.y + bv.y;
    o.z = s0.z + s1.z + s2.z + s3.z + bv.z;
    o.w = s0.w + s1.w + s2.w + s3.w + bv.w;
    out[i] = o;
}

extern "C" void kernel_launch(void* const* d_in, const int* in_sizes, int n_in,
                              void* d_out, int out_size, void* d_ws, size_t ws_size,
                              hipStream_t stream) {
    const float* x         = (const float*)d_in[0];
    const int*   qweight   = (const int*)d_in[1];
    const float* wscales   = (const float*)d_in[2];
    const float* lora_down = (const float*)d_in[3];
    const float* lora_up   = (const float*)d_in[4];
    const float* bias      = (const float*)d_in[5];

    char* wsp = (char*)d_ws;
    unsigned short* Ap = (unsigned short*)wsp;                 // 49*2048*16 B
    wsp += (size_t)NCHUNK * 2048 * 16;
    unsigned short* Wt = (unsigned short*)wsp;                 // 48*512*16 B
    wsp += (size_t)48 * 512 * 16;
    float* Lm = (float*)wsp;                                   // 256*32*4 B
    wsp += (size_t)T_DIM * R_DIM * 4;
    unsigned* Qp = (unsigned*)wsp;                             // N*K/8*4 B
    wsp += (size_t)N_DIM * (K_DIM / 8) * 4;
    float* P = (float*)wsp;                                    // NSPLIT*T*N*4 B

    hipMemsetAsync(Lm, 0, (size_t)T_DIM * R_DIM * sizeof(float), stream);
    pack_qw<<<(N_DIM * (K_DIM / 8)) / 256, 256, 0, stream>>>(qweight, Qp);
    build_wtail<<<(N_DIM * 64) / 256, 256, 0, stream>>>(lora_up, Wt);
    quant_act<<<(T_DIM * KG) / 4, 256, 0, stream>>>(x, Ap);
    lora_mid<<<K_DIM / 32, 256, 0, stream>>>(x, lora_down, Lm);
    pack_lora<<<(T_DIM * 64) / 256, 256, 0, stream>>>(Lm, Ap);
    gemm_main<<<dim3(48, NSPLIT), 256, 0, stream>>>(
        (const uint4*)Ap, Qp, wscales, (const uint4*)Wt, P);
    reduce_out<<<(T_DIM * N_DIM / 4) / 256, 256, 0, stream>>>(
        (const float4*)P, bias, (float4*)d_out);
}